// Round 1
// baseline (1808.436 us; speedup 1.0000x reference)
//
#include <hip/hip_runtime.h>
#include <hip/hip_bf16.h>

#define NPIECE 499

typedef __attribute__((ext_vector_type(8))) short bf16x8;
typedef __attribute__((ext_vector_type(4))) short s16x4;
typedef __attribute__((ext_vector_type(4))) float f32x4;

__device__ inline short f2bf(float x) {
    union { float f; unsigned u; } v; v.f = x;
    unsigned r = v.u + 0x7FFFu + ((v.u >> 16) & 1u);   // RNE fp32->bf16
    return (short)(r >> 16);
}

__device__ inline float fast_tanh(float x) {
    // tanh(x) = 1 - 2/(exp(2x)+1); inf-safe for large |x|
    float e = __expf(2.0f * x);
    return 1.0f - 2.0f * __builtin_amdgcn_rcpf(e + 1.0f);
}

__global__ void __launch_bounds__(512, 2)
cde_kernel(const float* __restrict__ times,
           const float* __restrict__ ca,  const float* __restrict__ cb,
           const float* __restrict__ c2c, const float* __restrict__ c3d,
           const float* __restrict__ initW, const float* __restrict__ initb,
           const float* __restrict__ W1,  const float* __restrict__ b1,
           const float* __restrict__ W2,  const float* __restrict__ b2,
           const float* __restrict__ linW, const float* __restrict__ linb,
           float* __restrict__ out)
{
    const int tid  = threadIdx.x;
    const int lane = tid & 63;
    const int wv   = tid >> 6;      // wave 0..7
    const int g    = lane >> 4;     // k-group 0..3
    const int col  = lane & 15;     // row (A) / col (B,D) within 16
    const int s0   = blockIdx.x * 2;

    // B-fragment staging buffers (k-mapping: k = 8*(m>>4) + e within 32-chunk,
    // col = m&15; same mapping used for A placement so any HW k-perm cancels)
    __shared__ __align__(16) short hbuf[4][64][8];   // h: K=128 -> 4 chunks
    __shared__ __align__(16) short zbuf[2][64][8];   // z: K=64  -> 2 chunks
    __shared__ __align__(16) float vbuf[2][512];     // v-preact fp32 (per-wave regions)
    __shared__ __align__(16) float zcur[2][64];
    __shared__ __align__(16) float dxbuf[2][3][2][8]; // [parity][slot][sample][ch]

    // ---------------- preload weight fragments (bf16, registers) -------------
    // layer2: wave owns o in [64*wv, 64*wv+64) : A = W2^T (o x k)
    bf16x8 a2[4][4];        // [ot][kk]
    float  binit2[4][4];    // [ot][r]
#pragma unroll
    for (int ot = 0; ot < 4; ++ot) {
        int o = 64 * wv + 16 * ot + col;
#pragma unroll
        for (int kk = 0; kk < 4; ++kk) {
            bf16x8 f;
#pragma unroll
            for (int e = 0; e < 8; ++e)
                f[e] = f2bf(W2[(32 * kk + 8 * g + e) * 512 + o]);
            a2[ot][kk] = f;
        }
#pragma unroll
        for (int r = 0; r < 4; ++r)
            binit2[ot][r] = b2[64 * wv + 16 * ot + 4 * g + r];
    }
    // layer1: wave owns h-tile [16*wv, 16*wv+16) : A = W1^T (h x k)
    bf16x8 a1[2];
#pragma unroll
    for (int kk = 0; kk < 2; ++kk) {
        bf16x8 f;
#pragma unroll
        for (int e = 0; e < 8; ++e)
            f[e] = f2bf(W1[(32 * kk + 8 * g + e) * 128 + 16 * wv + col]);
        a1[kk] = f;
    }
    float binit1[4];
#pragma unroll
    for (int r = 0; r < 4; ++r) binit1[r] = b1[16 * wv + 4 * g + r];

    // ---------------- z0 = X(t0) @ init_W + init_b ---------------------------
    if (tid < 128) {
        int s = tid >> 6, hid = tid & 63;
        float z = initb[hid];
#pragma unroll
        for (int c = 0; c < 8; ++c)
            z += ca[((s0 + s) * NPIECE + 0) * 8 + c] * initW[c * 64 + hid];
        zcur[s][hid] = z;
        int ksub = hid >> 5, kin = hid & 31;
        zbuf[ksub][((kin >> 3) << 4) | s][kin & 7] = f2bf(z);
    }
    __syncthreads();

    // RK4 state lives in the owner lane's registers: lane (m&3)==0 of wave wv
    // owns (s = lane>>5, hid = 8*wv + (m>>2))
    float zreg = 0.f, zsreg = 0.f;
    {
        int m = lane & 31, s = lane >> 5;
        if ((m & 3) == 0) zreg = zcur[s][8 * wv + (m >> 2)];
    }

    for (int i = 0; i < NPIECE; ++i) {
        const float t0 = times[i];
        const float t1 = times[i + 1];
        const float h  = t1 - t0;
        const int par  = i & 1;

        if (tid < 16) {   // dX/dt for the 3 distinct eval times of this step
            int s = tid >> 3, c = tid & 7;
            int rowbase = (s0 + s) * NPIECE * 8;
            // k1: t = times[i] -> piece max(i-1,0), frac = t0 - times[p0]
            int p0 = (i > 0) ? i - 1 : 0;
            float f0 = t0 - times[p0];
            int b0 = rowbase + p0 * 8 + c;
            dxbuf[par][0][s][c] = cb[b0] + (c2c[b0] + c3d[b0] * f0) * f0;
            // k2,k3: t = t0 + 0.5h -> piece i, frac = t - t0
            float th = t0 + 0.5f * h;
            float f1 = th - t0;
            int bi = rowbase + i * 8 + c;
            dxbuf[par][1][s][c] = cb[bi] + (c2c[bi] + c3d[bi] * f1) * f1;
            // k4: t = t0 + h; fp rollover may land in piece i+1
            float t3 = t0 + h;
            int bx; float f2v;
            if (i < NPIECE - 1 && t3 > t1) { bx = rowbase + (i + 1) * 8 + c; f2v = t3 - t1; }
            else                            { bx = bi;                        f2v = t3 - t0; }
            dxbuf[par][2][s][c] = cb[bx] + (c2c[bx] + c3d[bx] * f2v) * f2v;
        }

#pragma unroll
        for (int st = 0; st < 4; ++st) {
            const int dsel = (st == 0) ? 0 : ((st == 3) ? 2 : 1);
            __syncthreads();   // barrier A: zbuf (and dxbuf) ready

            // ---- layer1: h = relu(z @ W1 + b1) ----
            bf16x8 bz0 = *(const bf16x8*)&zbuf[0][lane][0];
            bf16x8 bz1 = *(const bf16x8*)&zbuf[1][lane][0];
            f32x4 acc1 = {binit1[0], binit1[1], binit1[2], binit1[3]};
            acc1 = __builtin_amdgcn_mfma_f32_16x16x32_bf16(a1[0], bz0, acc1, 0, 0, 0);
            acc1 = __builtin_amdgcn_mfma_f32_16x16x32_bf16(a1[1], bz1, acc1, 0, 0, 0);
            if (col < 2) {
                int h0 = 16 * wv + 4 * g;
                int ksub = h0 >> 5, kin = h0 & 31;
                s16x4 t;
                t[0] = f2bf(fmaxf(acc1[0], 0.f));
                t[1] = f2bf(fmaxf(acc1[1], 0.f));
                t[2] = f2bf(fmaxf(acc1[2], 0.f));
                t[3] = f2bf(fmaxf(acc1[3], 0.f));
                *(s16x4*)&hbuf[ksub][((kin >> 3) << 4) | col][kin & 7] = t;
            }
            __syncthreads();   // barrier B: hbuf ready

            // ---- layer2: v_pre = h @ W2 + b2 ----
            bf16x8 bh0 = *(const bf16x8*)&hbuf[0][lane][0];
            bf16x8 bh1 = *(const bf16x8*)&hbuf[1][lane][0];
            bf16x8 bh2 = *(const bf16x8*)&hbuf[2][lane][0];
            bf16x8 bh3 = *(const bf16x8*)&hbuf[3][lane][0];
            f32x4 c0 = {binit2[0][0], binit2[0][1], binit2[0][2], binit2[0][3]};
            f32x4 c1 = {binit2[1][0], binit2[1][1], binit2[1][2], binit2[1][3]};
            f32x4 c2r = {binit2[2][0], binit2[2][1], binit2[2][2], binit2[2][3]};
            f32x4 c3r = {binit2[3][0], binit2[3][1], binit2[3][2], binit2[3][3]};
            c0  = __builtin_amdgcn_mfma_f32_16x16x32_bf16(a2[0][0], bh0, c0, 0, 0, 0);
            c1  = __builtin_amdgcn_mfma_f32_16x16x32_bf16(a2[1][0], bh0, c1, 0, 0, 0);
            c2r = __builtin_amdgcn_mfma_f32_16x16x32_bf16(a2[2][0], bh0, c2r, 0, 0, 0);
            c3r = __builtin_amdgcn_mfma_f32_16x16x32_bf16(a2[3][0], bh0, c3r, 0, 0, 0);
            c0  = __builtin_amdgcn_mfma_f32_16x16x32_bf16(a2[0][1], bh1, c0, 0, 0, 0);
            c1  = __builtin_amdgcn_mfma_f32_16x16x32_bf16(a2[1][1], bh1, c1, 0, 0, 0);
            c2r = __builtin_amdgcn_mfma_f32_16x16x32_bf16(a2[2][1], bh1, c2r, 0, 0, 0);
            c3r = __builtin_amdgcn_mfma_f32_16x16x32_bf16(a2[3][1], bh1, c3r, 0, 0, 0);
            c0  = __builtin_amdgcn_mfma_f32_16x16x32_bf16(a2[0][2], bh2, c0, 0, 0, 0);
            c1  = __builtin_amdgcn_mfma_f32_16x16x32_bf16(a2[1][2], bh2, c1, 0, 0, 0);
            c2r = __builtin_amdgcn_mfma_f32_16x16x32_bf16(a2[2][2], bh2, c2r, 0, 0, 0);
            c3r = __builtin_amdgcn_mfma_f32_16x16x32_bf16(a2[3][2], bh2, c3r, 0, 0, 0);
            c0  = __builtin_amdgcn_mfma_f32_16x16x32_bf16(a2[0][3], bh3, c0, 0, 0, 0);
            c1  = __builtin_amdgcn_mfma_f32_16x16x32_bf16(a2[1][3], bh3, c1, 0, 0, 0);
            c2r = __builtin_amdgcn_mfma_f32_16x16x32_bf16(a2[2][3], bh3, c2r, 0, 0, 0);
            c3r = __builtin_amdgcn_mfma_f32_16x16x32_bf16(a2[3][3], bh3, c3r, 0, 0, 0);

            // stash valid columns (samples 0,1) to this wave's vbuf region
            if (col < 2) {
                *(f32x4*)&vbuf[col][64 * wv + 0  + 4 * g] = c0;
                *(f32x4*)&vbuf[col][64 * wv + 16 + 4 * g] = c1;
                *(f32x4*)&vbuf[col][64 * wv + 32 + 4 * g] = c2r;
                *(f32x4*)&vbuf[col][64 * wv + 48 + 4 * g] = c3r;
            }
            // same-wave LDS RAW: DS pipe is in-order per wave; fence the compiler
            asm volatile("s_waitcnt lgkmcnt(0)" ::: "memory");
            __builtin_amdgcn_wave_barrier();

            // ---- tanh + contraction dz[hid] = sum_i v[8*hid+i]*dx[i] (wave-local)
            {
                int m = lane & 31, s = lane >> 5;
                int o = 64 * wv + 2 * m;
                float2 vv = *(const float2*)&vbuf[s][o];
                float va = fast_tanh(vv.x);
                float vb = fast_tanh(vv.y);
                const float* dxp = &dxbuf[par][dsel][s][0];
                float d0 = dxp[(2 * m) & 7];
                float d1 = dxp[(2 * m + 1) & 7];
                float p = va * d0 + vb * d1;
                p += __shfl_xor(p, 1);
                p += __shfl_xor(p, 2);
                // lane with m%4==0 owns dz for (s, hid = 8*wv + m/4)
                if ((m & 3) == 0) {
                    int hid = 8 * wv + (m >> 2);
                    float k = p;
                    float zst;
                    if (st == 0)      { zsreg = k;             zst = zreg + 0.5f * h * k; }
                    else if (st == 1) { zsreg += 2.f * k;      zst = zreg + 0.5f * h * k; }
                    else if (st == 2) { zsreg += 2.f * k;      zst = zreg + h * k; }
                    else              { zsreg += k;            zst = zreg + (h / 6.f) * zsreg;
                                        zreg = zst;            zcur[s][hid] = zst; }
                    int ksub = hid >> 5, kin = hid & 31;
                    zbuf[ksub][((kin >> 3) << 4) | s][kin & 7] = f2bf(zst);
                }
            }
        }
    }

    __syncthreads();
    // ---- readout: sigmoid(z @ lin_W + lin_b) ----
    if (tid < 2) {
        float acc = linb[0];
        for (int hd = 0; hd < 64; ++hd) acc += zcur[tid][hd] * linW[hd];
        out[s0 + tid] = 1.0f / (1.0f + __expf(-acc));
    }
}

extern "C" void kernel_launch(void* const* d_in, const int* in_sizes, int n_in,
                              void* d_out, int out_size, void* d_ws, size_t ws_size,
                              hipStream_t stream) {
    (void)in_sizes; (void)n_in; (void)d_ws; (void)ws_size; (void)out_size;
    const float* times = (const float*)d_in[0];
    const float* ca    = (const float*)d_in[1];
    const float* cb    = (const float*)d_in[2];
    const float* c2c   = (const float*)d_in[3];
    const float* c3d   = (const float*)d_in[4];
    const float* initW = (const float*)d_in[5];
    const float* initb = (const float*)d_in[6];
    const float* W1    = (const float*)d_in[7];
    const float* b1    = (const float*)d_in[8];
    const float* W2    = (const float*)d_in[9];
    const float* b2    = (const float*)d_in[10];
    const float* linW  = (const float*)d_in[11];
    const float* linb  = (const float*)d_in[12];
    cde_kernel<<<256, 512, 0, stream>>>(times, ca, cb, c2c, c3d, initW, initb,
                                        W1, b1, W2, b2, linW, linb, (float*)d_out);
}